// Round 5
// baseline (597.554 us; speedup 1.0000x reference)
//
#include <hip/hip_runtime.h>
#include <hip/hip_bf16.h>

#define B_ 4
#define S_ 128
#define D_ 512
#define H_ 8
#define DH_ 64
#define F_ 2048
#define R_ 8

// ---------------- LayerNorm 1: xn = LN(x) -> fp32 ----------------
__global__ void ln1_kernel(const float* __restrict__ x, const float* __restrict__ g,
                           const float* __restrict__ be, float* __restrict__ xn) {
    int row = blockIdx.x;            // b*S + s
    int t = threadIdx.x;             // 256 threads, 2 elems each
    __shared__ float red[256];
    const float* xr = x + row * D_;
    float v0 = xr[t];
    float v1 = xr[t + 256];
    red[t] = v0 + v1;
    __syncthreads();
    for (int off = 128; off > 0; off >>= 1) {
        if (t < off) red[t] += red[t + off];
        __syncthreads();
    }
    float mean = red[0] * (1.0f / D_);
    __syncthreads();
    float d0 = v0 - mean, d1 = v1 - mean;
    red[t] = d0 * d0 + d1 * d1;
    __syncthreads();
    for (int off = 128; off > 0; off >>= 1) {
        if (t < off) red[t] += red[t + off];
        __syncthreads();
    }
    float rs = rsqrtf(red[0] * (1.0f / D_) + 1e-5f);
    float* o = xn + row * D_;
    o[t]       = d0 * rs * g[t]       + be[t];
    o[t + 256] = d1 * rs * g[t + 256] + be[t + 256];
}

// ---------------- Generic GEMM: C[M,N] = A[M,K] @ B[K,N] + bias, opt relu (all fp32) ----------------
__global__ void gemm_kernel(const float* __restrict__ A, const float* __restrict__ Bm,
                            const float* __restrict__ bias, float* __restrict__ C,
                            int M, int N, int K, int relu) {
    __shared__ float As[32][33];
    __shared__ float Bs[32][33];
    int tid = threadIdx.x;
    int ty = tid >> 4, tx = tid & 15;
    int rowBase = blockIdx.y * 32;
    int colBase = blockIdx.x * 32;
    float acc00 = 0.f, acc01 = 0.f, acc10 = 0.f, acc11 = 0.f;
    for (int k0 = 0; k0 < K; k0 += 32) {
#pragma unroll
        for (int i = 0; i < 4; ++i) {
            int idx = tid + i * 256;
            int r = idx >> 5, c = idx & 31;
            As[r][c] = A[(rowBase + r) * (long)K + k0 + c];
            Bs[r][c] = Bm[(k0 + r) * (long)N + colBase + c];
        }
        __syncthreads();
#pragma unroll
        for (int kk = 0; kk < 32; ++kk) {
            float a0 = As[ty][kk], a1 = As[ty + 16][kk];
            float b0 = Bs[kk][tx], b1 = Bs[kk][tx + 16];
            acc00 += a0 * b0; acc01 += a0 * b1;
            acc10 += a1 * b0; acc11 += a1 * b1;
        }
        __syncthreads();
    }
    float bi0 = bias ? bias[colBase + tx]      : 0.f;
    float bi1 = bias ? bias[colBase + tx + 16] : 0.f;
    float r00 = acc00 + bi0, r01 = acc01 + bi1, r10 = acc10 + bi0, r11 = acc11 + bi1;
    if (relu) {
        r00 = fmaxf(r00, 0.f); r01 = fmaxf(r01, 0.f);
        r10 = fmaxf(r10, 0.f); r11 = fmaxf(r11, 0.f);
    }
    C[(rowBase + ty) * (long)N + colBase + tx]           = r00;
    C[(rowBase + ty) * (long)N + colBase + tx + 16]      = r01;
    C[(rowBase + ty + 16) * (long)N + colBase + tx]      = r10;
    C[(rowBase + ty + 16) * (long)N + colBase + tx + 16] = r11;
}

// ---------------- Attention: per (b,h,i) row: scores -> softmax -> attn row + ctx ----------------
__global__ void attn_kernel(const float* __restrict__ q, const float* __restrict__ k,
                            const float* __restrict__ v, float* __restrict__ attn,
                            float* __restrict__ ctx) {
    int blk = blockIdx.x;            // (b*H + h)*S + i
    int i = blk % S_;
    int bh = blk / S_;
    int h = bh % H_;
    int b = bh / H_;
    int t = threadIdx.x;             // 128 threads
    __shared__ float qs[DH_];
    __shared__ float sc[S_];
    __shared__ float red[S_];
    if (t < DH_) qs[t] = q[(b * S_ + i) * D_ + h * DH_ + t];
    __syncthreads();
    {
        const float* krow = k + (b * S_ + t) * D_ + h * DH_;
        float acc = 0.f;
#pragma unroll 8
        for (int d = 0; d < DH_; ++d) acc += qs[d] * krow[d];
        sc[t] = acc * 0.125f;        // / sqrt(64)
    }
    __syncthreads();
    red[t] = sc[t];
    __syncthreads();
    for (int off = 64; off > 0; off >>= 1) {
        if (t < off) red[t] = fmaxf(red[t], red[t + off]);
        __syncthreads();
    }
    float mx = red[0];
    __syncthreads();
    float e = expf(sc[t] - mx);
    red[t] = e;
    __syncthreads();
    for (int off = 64; off > 0; off >>= 1) {
        if (t < off) red[t] += red[t + off];
        __syncthreads();
    }
    float p = e / red[0];
    __syncthreads();
    sc[t] = p;
    attn[((b * H_ + h) * (long)S_ + i) * S_ + t] = p;
    __syncthreads();
    if (t < DH_) {
        const float* vbase = v + b * S_ * D_ + h * DH_ + t;
        float acc = 0.f;
        for (int j = 0; j < S_; ++j) acc += sc[j] * vbase[j * D_];
        ctx[(b * S_ + i) * D_ + h * DH_ + t] = acc;
    }
}

// ---------------- Adjacency: adj[b,i,j] = (mean_h attn > 0.1) && i!=j ----------------
__global__ void adj_kernel(const float* __restrict__ attn, int* __restrict__ adj) {
    int idx = blockIdx.x * 256 + threadIdx.x;   // b*S*S + i*S + j
    if (idx >= B_ * S_ * S_) return;
    int j = idx % S_;
    int bi = idx / S_;
    int i = bi % S_;
    int b = bi / S_;
    float s = 0.f;
#pragma unroll
    for (int h = 0; h < H_; ++h) s += attn[((b * H_ + h) * (long)S_ + i) * S_ + j];
    s *= (1.0f / H_);
    adj[idx] = (s > 0.1f && i != j) ? 1 : 0;
}

// ---------------- Relation classifier at edges only ----------------
__global__ void edge_kernel(const float* __restrict__ a_part, const float* __restrict__ b_part,
                            const float* __restrict__ rc_b1, const float* __restrict__ rc_w2,
                            const float* __restrict__ rc_b2, const int* __restrict__ adj,
                            int* __restrict__ rel) {
    int blk = blockIdx.x;            // b*S*S + u*S + v
    int lane = threadIdx.x;          // 64 (one wave; adj[blk] uniform across block)
    if (adj[blk] == 0) {
        if (lane == 0) rel[blk] = 0;
        return;
    }
    __shared__ float sred[64][R_ + 1];
    __shared__ float logit[R_];
    int vv = blk % S_;
    int bu = blk / S_;
    int u = bu % S_;
    int b = bu / S_;
    const float* ap = a_part + (b * S_ + u) * D_;
    const float* bp = b_part + (b * S_ + vv) * D_;
    float lp[R_];
#pragma unroll
    for (int r = 0; r < R_; ++r) lp[r] = 0.f;
    for (int jj = 0; jj < D_ / 64; ++jj) {
        int d = lane + jj * 64;
        float hv = fmaxf(ap[d] + bp[d] + rc_b1[d], 0.f);
#pragma unroll
        for (int r = 0; r < R_; ++r) lp[r] += hv * rc_w2[d * R_ + r];
    }
#pragma unroll
    for (int r = 0; r < R_; ++r) sred[lane][r] = lp[r];
    __syncthreads();
    if (lane < R_) {
        float tot = rc_b2[lane];
        for (int i = 0; i < 64; ++i) tot += sred[i][lane];
        logit[lane] = tot;
    }
    __syncthreads();
    if (lane == 0) {
        float best = logit[0];
        int bi = 0;
#pragma unroll
        for (int r = 1; r < R_; ++r) {
            if (logit[r] > best) { best = logit[r]; bi = r; }  // strict > = first max (numpy)
        }
        rel[blk] = bi;               // 0 == NONE -> no edge downstream
    }
}

// ---------------- Build M[b,v, r*D+d] = sum_u [rel(u,v)==r] nu[b,u,d] ----------------
__global__ void mbuild_kernel(const float* __restrict__ nu, const int* __restrict__ rel,
                              float* __restrict__ M) {
    int blk = blockIdx.x;            // b*S + v
    int vv = blk % S_;
    int b = blk / S_;
    int t = threadIdx.x;             // 128
    float* Mrow = M + (long)blk * (R_ * D_);
    for (int i = t; i < R_ * D_; i += 128) Mrow[i] = 0.f;
    __syncthreads();
    const int* relbase = rel + (long)b * S_ * S_ + vv;   // rel[b,u,v], stride S_ over u
    for (int u = 0; u < S_; ++u) {
        int r = relbase[u * S_];
        if (r >= 1 && r < R_) {
            const float* nurow = nu + (b * S_ + u) * D_;
            for (int d = t; d < D_; d += 128) Mrow[r * D_ + d] += nurow[d];
        }
    }
}

// ---------------- reasoned = nu + agg (in-place into nu) ----------------
__global__ void add_kernel(float* __restrict__ nu, const float* __restrict__ agg, int n) {
    int i = blockIdx.x * 256 + threadIdx.x;
    if (i < n) nu[i] += agg[i];
}

// ---------------- LayerNorm 2: out = LN(x + y) -> fp32 (reference output dtype!) ----------------
__global__ void ln2_kernel(const float* __restrict__ x, const float* __restrict__ y,
                           const float* __restrict__ g, const float* __restrict__ be,
                           float* __restrict__ out) {
    int row = blockIdx.x;
    int t = threadIdx.x;             // 256
    __shared__ float red[256];
    float v0 = x[row * D_ + t]       + y[row * D_ + t];
    float v1 = x[row * D_ + t + 256] + y[row * D_ + t + 256];
    red[t] = v0 + v1;
    __syncthreads();
    for (int off = 128; off > 0; off >>= 1) {
        if (t < off) red[t] += red[t + off];
        __syncthreads();
    }
    float mean = red[0] * (1.0f / D_);
    __syncthreads();
    float d0 = v0 - mean, d1 = v1 - mean;
    red[t] = d0 * d0 + d1 * d1;
    __syncthreads();
    for (int off = 128; off > 0; off >>= 1) {
        if (t < off) red[t] += red[t + off];
        __syncthreads();
    }
    float rs = rsqrtf(red[0] * (1.0f / D_) + 1e-5f);
    out[row * D_ + t]       = d0 * rs * g[t]       + be[t];
    out[row * D_ + t + 256] = d1 * rs * g[t + 256] + be[t + 256];
}

extern "C" void kernel_launch(void* const* d_in, const int* in_sizes, int n_in,
                              void* d_out, int out_size, void* d_ws, size_t ws_size,
                              hipStream_t stream) {
    // Inputs fp32 (proven by r2-vs-r3 differential); output fp32 (reference output dtype).
    const float* x     = (const float*)d_in[0];
    const float* ln1_g = (const float*)d_in[1];
    const float* ln1_b = (const float*)d_in[2];
    const float* wq    = (const float*)d_in[3];
    const float* bq    = (const float*)d_in[4];
    const float* wk    = (const float*)d_in[5];
    const float* bk    = (const float*)d_in[6];
    const float* wv    = (const float*)d_in[7];
    const float* bv    = (const float*)d_in[8];
    const float* wo    = (const float*)d_in[9];
    const float* bo    = (const float*)d_in[10];
    const float* w1    = (const float*)d_in[11];
    const float* b1    = (const float*)d_in[12];
    const float* w2    = (const float*)d_in[13];
    const float* b2    = (const float*)d_in[14];
    const float* rc_w1 = (const float*)d_in[15];
    const float* rc_b1 = (const float*)d_in[16];
    const float* rc_w2 = (const float*)d_in[17];
    const float* rc_b2 = (const float*)d_in[18];
    const float* kg_w  = (const float*)d_in[19];
    const float* s2n_w = (const float*)d_in[20];
    const float* s2n_b = (const float*)d_in[21];
    const float* ln2_g = (const float*)d_in[22];
    const float* ln2_b = (const float*)d_in[23];
    float* out = (float*)d_out;

    const int BS  = B_ * S_;          // 512
    const int BSD = BS * D_;          // 262144 floats (1 MB)

    // ---- Workspace: 14.2 MB. adj/rel first | BIG 8 MB (attn->hidden->Mbuf) | S0..S4 overlay.
    int* adj   = (int*)d_ws;              // 65536 ints
    int* rel   = adj + B_ * S_ * S_;      // 65536 ints
    float* BIG = (float*)(rel + B_ * S_ * S_);   // 2,097,152 floats
    float* S0  = BIG + 2097152;
    float* S1  = S0 + BSD;
    float* S2  = S1 + BSD;
    float* S3  = S2 + BSD;
    float* S4  = S3 + BSD;

    // Overlay assignments (lifetimes disjoint, audited):
    float* xn       = S0;   // steps 1-2
    float* q        = S1;   // 2-3
    float* k        = S2;   // 2-3
    float* v        = S3;   // 2-3
    float* attn     = BIG;  // 3-4
    float* ctx      = S4;   // 3-5
    float* attn_out = S0;   // 5-6
    float* hidden   = BIG;  // 6-7
    float* nu       = S2;   // 7-13
    float* a_part   = S0;   // 8-9
    float* b_part   = S1;   // 8-9
    float* Mbuf     = BIG;  // 10-11
    float* agg      = S1;   // 11-12
    float* y        = S0;   // 13-14

    dim3 g512(D_ / 32, BS / 32);      // (16,16)

    // 1. LN1
    hipLaunchKernelGGL(ln1_kernel, dim3(BS), dim3(256), 0, stream, x, ln1_g, ln1_b, xn);
    // 2. Q,K,V projections
    hipLaunchKernelGGL(gemm_kernel, g512, dim3(256), 0, stream, xn, wq, bq, q, BS, D_, D_, 0);
    hipLaunchKernelGGL(gemm_kernel, g512, dim3(256), 0, stream, xn, wk, bk, k, BS, D_, D_, 0);
    hipLaunchKernelGGL(gemm_kernel, g512, dim3(256), 0, stream, xn, wv, bv, v, BS, D_, D_, 0);
    // 3. attention -> attn(BIG), ctx(S4)
    hipLaunchKernelGGL(attn_kernel, dim3(B_ * H_ * S_), dim3(S_), 0, stream, q, k, v, attn, ctx);
    // 4. adjacency
    hipLaunchKernelGGL(adj_kernel, dim3(B_ * S_ * S_ / 256), dim3(256), 0, stream, attn, adj);
    // 5. output projection: ctx -> attn_out(S0)
    hipLaunchKernelGGL(gemm_kernel, g512, dim3(256), 0, stream, ctx, wo, bo, attn_out, BS, D_, D_, 0);
    // 6. FFN1: attn_out -> hidden(BIG)
    hipLaunchKernelGGL(gemm_kernel, dim3(F_ / 32, BS / 32), dim3(256), 0, stream,
                       attn_out, w1, b1, hidden, BS, F_, D_, 1);
    // 7. FFN2: hidden -> nu(S2)
    hipLaunchKernelGGL(gemm_kernel, g512, dim3(256), 0, stream, hidden, w2, b2, nu, BS, D_, F_, 0);
    // 8. relation classifier halves: nu -> a_part(S0), b_part(S1)
    hipLaunchKernelGGL(gemm_kernel, g512, dim3(256), 0, stream, nu, rc_w1, (const float*)nullptr,
                       a_part, BS, D_, D_, 0);
    hipLaunchKernelGGL(gemm_kernel, g512, dim3(256), 0, stream, nu, rc_w1 + D_ * D_,
                       (const float*)nullptr, b_part, BS, D_, D_, 0);
    // 9. edges -> rel
    hipLaunchKernelGGL(edge_kernel, dim3(B_ * S_ * S_), dim3(64), 0, stream,
                       a_part, b_part, rc_b1, rc_w2, rc_b2, adj, rel);
    // 10. RGCN aggregate: nu, rel -> Mbuf(BIG)
    hipLaunchKernelGGL(mbuild_kernel, dim3(BS), dim3(128), 0, stream, nu, rel, Mbuf);
    // 11. Mbuf @ kg_w -> agg(S1)
    hipLaunchKernelGGL(gemm_kernel, g512, dim3(256), 0, stream, Mbuf, kg_w,
                       (const float*)nullptr, agg, BS, D_, R_ * D_, 0);
    // 12. reasoned = nu + agg (in-place in nu)
    hipLaunchKernelGGL(add_kernel, dim3(BSD / 256), dim3(256), 0, stream, nu, agg, BSD);
    // 13. symbolic-to-neural: nu -> y(S0)
    hipLaunchKernelGGL(gemm_kernel, g512, dim3(256), 0, stream, nu, s2n_w, s2n_b, y, BS, D_, D_, 0);
    // 14. LN2 -> out (fp32)
    hipLaunchKernelGGL(ln2_kernel, dim3(BS), dim3(256), 0, stream, x, y, ln2_g, ln2_b, out);
}

// Round 6
// 415.953 us; speedup vs baseline: 1.4366x; 1.4366x over previous
//
#include <hip/hip_runtime.h>
#include <hip/hip_bf16.h>

#define B_ 4
#define S_ 128
#define D_ 512
#define H_ 8
#define DH_ 64
#define F_ 2048
#define R_ 8

#define TS 64          // output tile 64x64
#define BK 32          // k-tile
#define LDP (TS + 4)   // LDS row pad: 68 floats = 272 B (16B-aligned rows)

// ---------------- LayerNorm 1 ----------------
__global__ void ln1_kernel(const float* __restrict__ x, const float* __restrict__ g,
                           const float* __restrict__ be, float* __restrict__ xn) {
    int row = blockIdx.x;
    int t = threadIdx.x;             // 256
    __shared__ float red[256];
    const float* xr = x + row * D_;
    float v0 = xr[t];
    float v1 = xr[t + 256];
    red[t] = v0 + v1;
    __syncthreads();
    for (int off = 128; off > 0; off >>= 1) {
        if (t < off) red[t] += red[t + off];
        __syncthreads();
    }
    float mean = red[0] * (1.0f / D_);
    __syncthreads();
    float d0 = v0 - mean, d1 = v1 - mean;
    red[t] = d0 * d0 + d1 * d1;
    __syncthreads();
    for (int off = 128; off > 0; off >>= 1) {
        if (t < off) red[t] += red[t + off];
        __syncthreads();
    }
    float rs = rsqrtf(red[0] * (1.0f / D_) + 1e-5f);
    float* o = xn + row * D_;
    o[t]       = d0 * rs * g[t]       + be[t];
    o[t + 256] = d1 * rs * g[t + 256] + be[t + 256];
}

// ---------------- 64x64-tile GEMM core (device inline) ----------------
// Computes acc[4][4] for this thread over K range [k_start, k_start+k_len).
__device__ __forceinline__ void gemm64_core(const float* __restrict__ A,
                                            const float* __restrict__ Bm,
                                            int K, int N, int rowBase, int colBase,
                                            int k_start, int k_len,
                                            float acc[4][4],
                                            float As[BK][LDP], float Bs[BK][LDP]) {
    int tid = threadIdx.x;
    int tx = tid & 15, ty = tid >> 4;
    for (int k0 = k_start; k0 < k_start + k_len; k0 += BK) {
#pragma unroll
        for (int i = 0; i < 2; ++i) {
            int f4 = tid + i * 256;                 // 0..511
            int r  = f4 >> 3, kv = f4 & 7;          // A: 64 rows x 8 float4 (along k)
            const float4 av = *(const float4*)&A[(long)(rowBase + r) * K + k0 + kv * 4];
            As[kv * 4 + 0][r] = av.x;
            As[kv * 4 + 1][r] = av.y;
            As[kv * 4 + 2][r] = av.z;
            As[kv * 4 + 3][r] = av.w;
            int rb = f4 >> 4, cv = f4 & 15;         // B: 32 rows x 16 float4 (along n)
            *(float4*)&Bs[rb][cv * 4] =
                *(const float4*)&Bm[(long)(k0 + rb) * N + colBase + cv * 4];
        }
        __syncthreads();
#pragma unroll
        for (int k = 0; k < BK; ++k) {
            float4 a = *(const float4*)&As[k][ty * 4];
            float4 b = *(const float4*)&Bs[k][tx * 4];
            float a4[4] = {a.x, a.y, a.z, a.w};
            float b4[4] = {b.x, b.y, b.z, b.w};
#pragma unroll
            for (int i = 0; i < 4; ++i)
#pragma unroll
                for (int j = 0; j < 4; ++j) acc[i][j] += a4[i] * b4[j];
        }
        __syncthreads();
    }
}

// Plain: C = A@B + bias, optional relu. grid (N/64, M/64)
__global__ __launch_bounds__(256) void gemm64_kernel(const float* __restrict__ A,
                                                     const float* __restrict__ Bm,
                                                     const float* __restrict__ bias,
                                                     float* __restrict__ C,
                                                     int N, int K, int relu) {
    __shared__ float As[BK][LDP];
    __shared__ float Bs[BK][LDP];
    int tx = threadIdx.x & 15, ty = threadIdx.x >> 4;
    int rowBase = blockIdx.y * TS, colBase = blockIdx.x * TS;
    float acc[4][4] = {};
    gemm64_core(A, Bm, K, N, rowBase, colBase, 0, K, acc, As, Bs);
    float bi[4];
#pragma unroll
    for (int j = 0; j < 4; ++j) bi[j] = bias ? bias[colBase + tx * 4 + j] : 0.f;
#pragma unroll
    for (int i = 0; i < 4; ++i) {
        float* crow = C + (long)(rowBase + ty * 4 + i) * N + colBase + tx * 4;
#pragma unroll
        for (int j = 0; j < 4; ++j) {
            float v = acc[i][j] + bi[j];
            if (relu) v = fmaxf(v, 0.f);
            crow[j] = v;
        }
    }
}

// z-batched weights: C+z*M*N = A @ W[z] + b[z]. grid (N/64, M/64, nW). N=512 here.
__global__ __launch_bounds__(256) void gemm64_zw_kernel(const float* __restrict__ A,
                                                        const float* __restrict__ W0,
                                                        const float* __restrict__ W1,
                                                        const float* __restrict__ W2,
                                                        const float* __restrict__ b0,
                                                        const float* __restrict__ b1,
                                                        const float* __restrict__ b2,
                                                        float* __restrict__ Cbase,
                                                        int M, int N, int K) {
    __shared__ float As[BK][LDP];
    __shared__ float Bs[BK][LDP];
    int z = blockIdx.z;
    const float* Bm   = (z == 0) ? W0 : (z == 1) ? W1 : W2;
    const float* bias = (z == 0) ? b0 : (z == 1) ? b1 : b2;
    float* C = Cbase + (long)z * M * N;
    int tx = threadIdx.x & 15, ty = threadIdx.x >> 4;
    int rowBase = blockIdx.y * TS, colBase = blockIdx.x * TS;
    float acc[4][4] = {};
    gemm64_core(A, Bm, K, N, rowBase, colBase, 0, K, acc, As, Bs);
    float bi[4];
#pragma unroll
    for (int j = 0; j < 4; ++j) bi[j] = bias ? bias[colBase + tx * 4 + j] : 0.f;
#pragma unroll
    for (int i = 0; i < 4; ++i) {
        float* crow = C + (long)(rowBase + ty * 4 + i) * N + colBase + tx * 4;
#pragma unroll
        for (int j = 0; j < 4; ++j) crow[j] = acc[i][j] + bi[j];
    }
}

// Split-K: grid (N/64, M/64, ksplit); C pre-zeroed; partials atomicAdd'ed.
// bias (if any) contributed by z==0 block. No relu support.
__global__ __launch_bounds__(256) void gemm64_sk_kernel(const float* __restrict__ A,
                                                        const float* __restrict__ Bm,
                                                        const float* __restrict__ bias,
                                                        float* __restrict__ C,
                                                        int N, int K) {
    __shared__ float As[BK][LDP];
    __shared__ float Bs[BK][LDP];
    int ks = gridDim.z, z = blockIdx.z;
    int kLen = K / ks, kStart = z * kLen;
    int tx = threadIdx.x & 15, ty = threadIdx.x >> 4;
    int rowBase = blockIdx.y * TS, colBase = blockIdx.x * TS;
    float acc[4][4] = {};
    gemm64_core(A, Bm, K, N, rowBase, colBase, kStart, kLen, acc, As, Bs);
    float bi[4];
#pragma unroll
    for (int j = 0; j < 4; ++j)
        bi[j] = (bias && z == 0) ? bias[colBase + tx * 4 + j] : 0.f;
#pragma unroll
    for (int i = 0; i < 4; ++i) {
        float* crow = C + (long)(rowBase + ty * 4 + i) * N + colBase + tx * 4;
#pragma unroll
        for (int j = 0; j < 4; ++j) atomicAdd(&crow[j], acc[i][j] + bi[j]);
    }
}

// ---------------- Attention ----------------
__global__ void attn_kernel(const float* __restrict__ q, const float* __restrict__ k,
                            const float* __restrict__ v, float* __restrict__ attn,
                            float* __restrict__ ctx) {
    int blk = blockIdx.x;            // (b*H + h)*S + i
    int i = blk % S_;
    int bh = blk / S_;
    int h = bh % H_;
    int b = bh / H_;
    int t = threadIdx.x;             // 128
    __shared__ float qs[DH_];
    __shared__ float sc[S_];
    __shared__ float red[S_];
    if (t < DH_) qs[t] = q[(b * S_ + i) * D_ + h * DH_ + t];
    __syncthreads();
    {
        const float* krow = k + (b * S_ + t) * D_ + h * DH_;
        float acc = 0.f;
#pragma unroll 8
        for (int d = 0; d < DH_; ++d) acc += qs[d] * krow[d];
        sc[t] = acc * 0.125f;
    }
    __syncthreads();
    red[t] = sc[t];
    __syncthreads();
    for (int off = 64; off > 0; off >>= 1) {
        if (t < off) red[t] = fmaxf(red[t], red[t + off]);
        __syncthreads();
    }
    float mx = red[0];
    __syncthreads();
    float e = expf(sc[t] - mx);
    red[t] = e;
    __syncthreads();
    for (int off = 64; off > 0; off >>= 1) {
        if (t < off) red[t] += red[t + off];
        __syncthreads();
    }
    float p = e / red[0];
    __syncthreads();
    sc[t] = p;
    attn[((b * H_ + h) * (long)S_ + i) * S_ + t] = p;
    __syncthreads();
    if (t < DH_) {
        const float* vbase = v + b * S_ * D_ + h * DH_ + t;
        float acc = 0.f;
        for (int j = 0; j < S_; ++j) acc += sc[j] * vbase[j * D_];
        ctx[(b * S_ + i) * D_ + h * DH_ + t] = acc;
    }
}

// ---------------- Adjacency ----------------
__global__ void adj_kernel(const float* __restrict__ attn, int* __restrict__ adj) {
    int idx = blockIdx.x * 256 + threadIdx.x;
    if (idx >= B_ * S_ * S_) return;
    int j = idx % S_;
    int bi = idx / S_;
    int i = bi % S_;
    int b = bi / S_;
    float s = 0.f;
#pragma unroll
    for (int h = 0; h < H_; ++h) s += attn[((b * H_ + h) * (long)S_ + i) * S_ + j];
    s *= (1.0f / H_);
    adj[idx] = (s > 0.1f && i != j) ? 1 : 0;
}

// ---------------- Relation classifier at edges ----------------
__global__ void edge_kernel(const float* __restrict__ a_part, const float* __restrict__ b_part,
                            const float* __restrict__ rc_b1, const float* __restrict__ rc_w2,
                            const float* __restrict__ rc_b2, const int* __restrict__ adj,
                            int* __restrict__ rel) {
    int blk = blockIdx.x;            // b*S*S + u*S + v
    int lane = threadIdx.x;          // 64
    if (adj[blk] == 0) {
        if (lane == 0) rel[blk] = 0;
        return;
    }
    __shared__ float sred[64][R_ + 1];
    __shared__ float logit[R_];
    int vv = blk % S_;
    int bu = blk / S_;
    int u = bu % S_;
    int b = bu / S_;
    const float* ap = a_part + (b * S_ + u) * D_;
    const float* bp = b_part + (b * S_ + vv) * D_;
    float lp[R_];
#pragma unroll
    for (int r = 0; r < R_; ++r) lp[r] = 0.f;
    for (int jj = 0; jj < D_ / 64; ++jj) {
        int d = lane + jj * 64;
        float hv = fmaxf(ap[d] + bp[d] + rc_b1[d], 0.f);
#pragma unroll
        for (int r = 0; r < R_; ++r) lp[r] += hv * rc_w2[d * R_ + r];
    }
#pragma unroll
    for (int r = 0; r < R_; ++r) sred[lane][r] = lp[r];
    __syncthreads();
    if (lane < R_) {
        float tot = rc_b2[lane];
        for (int i = 0; i < 64; ++i) tot += sred[i][lane];
        logit[lane] = tot;
    }
    __syncthreads();
    if (lane == 0) {
        float best = logit[0];
        int bi = 0;
#pragma unroll
        for (int r = 1; r < R_; ++r) {
            if (logit[r] > best) { best = logit[r]; bi = r; }
        }
        rel[blk] = bi;
    }
}

// ---------------- M[b,v, r*D+d] = sum_u [rel(u,v)==r] nu[b,u,d] ----------------
__global__ void mbuild_kernel(const float* __restrict__ nu, const int* __restrict__ rel,
                              float* __restrict__ M) {
    int blk = blockIdx.x;            // b*S + v
    int vv = blk % S_;
    int b = blk / S_;
    int t = threadIdx.x;             // 128
    float* Mrow = M + (long)blk * (R_ * D_);
    for (int i = t; i < R_ * D_; i += 128) Mrow[i] = 0.f;
    __syncthreads();
    const int* relbase = rel + (long)b * S_ * S_ + vv;
    for (int u = 0; u < S_; ++u) {
        int r = relbase[u * S_];
        if (r >= 1 && r < R_) {
            const float* nurow = nu + (b * S_ + u) * D_;
            for (int d = t; d < D_; d += 128) Mrow[r * D_ + d] += nurow[d];
        }
    }
}

// ---------------- nu += agg ----------------
__global__ void add_kernel(float* __restrict__ nu, const float* __restrict__ agg, int n) {
    int i = blockIdx.x * 256 + threadIdx.x;
    if (i < n) nu[i] += agg[i];
}

// ---------------- LayerNorm 2 -> fp32 out ----------------
__global__ void ln2_kernel(const float* __restrict__ x, const float* __restrict__ y,
                           const float* __restrict__ g, const float* __restrict__ be,
                           float* __restrict__ out) {
    int row = blockIdx.x;
    int t = threadIdx.x;             // 256
    __shared__ float red[256];
    float v0 = x[row * D_ + t]       + y[row * D_ + t];
    float v1 = x[row * D_ + t + 256] + y[row * D_ + t + 256];
    red[t] = v0 + v1;
    __syncthreads();
    for (int off = 128; off > 0; off >>= 1) {
        if (t < off) red[t] += red[t + off];
        __syncthreads();
    }
    float mean = red[0] * (1.0f / D_);
    __syncthreads();
    float d0 = v0 - mean, d1 = v1 - mean;
    red[t] = d0 * d0 + d1 * d1;
    __syncthreads();
    for (int off = 128; off > 0; off >>= 1) {
        if (t < off) red[t] += red[t + off];
        __syncthreads();
    }
    float rs = rsqrtf(red[0] * (1.0f / D_) + 1e-5f);
    out[row * D_ + t]       = d0 * rs * g[t]       + be[t];
    out[row * D_ + t + 256] = d1 * rs * g[t + 256] + be[t + 256];
}

extern "C" void kernel_launch(void* const* d_in, const int* in_sizes, int n_in,
                              void* d_out, int out_size, void* d_ws, size_t ws_size,
                              hipStream_t stream) {
    const float* x     = (const float*)d_in[0];
    const float* ln1_g = (const float*)d_in[1];
    const float* ln1_b = (const float*)d_in[2];
    const float* wq    = (const float*)d_in[3];
    const float* bq    = (const float*)d_in[4];
    const float* wk    = (const float*)d_in[5];
    const float* bk    = (const float*)d_in[6];
    const float* wv    = (const float*)d_in[7];
    const float* bv    = (const float*)d_in[8];
    const float* wo    = (const float*)d_in[9];
    const float* bo    = (const float*)d_in[10];
    const float* w1    = (const float*)d_in[11];
    const float* b1    = (const float*)d_in[12];
    const float* w2    = (const float*)d_in[13];
    const float* b2    = (const float*)d_in[14];
    const float* rc_w1 = (const float*)d_in[15];
    const float* rc_b1 = (const float*)d_in[16];
    const float* rc_w2 = (const float*)d_in[17];
    const float* rc_b2 = (const float*)d_in[18];
    const float* kg_w  = (const float*)d_in[19];
    const float* s2n_w = (const float*)d_in[20];
    const float* s2n_b = (const float*)d_in[21];
    const float* ln2_g = (const float*)d_in[22];
    const float* ln2_b = (const float*)d_in[23];
    float* out = (float*)d_out;

    const int BS  = B_ * S_;          // 512
    const int BSD = BS * D_;          // 262144 floats (1 MB)

    // ---- Workspace 14.2 MB: adj/rel | BIG 8MB (attn->hidden->Mbuf) | S0..S4 ----
    int* adj   = (int*)d_ws;
    int* rel   = adj + B_ * S_ * S_;
    float* BIG = (float*)(rel + B_ * S_ * S_);
    float* S0  = BIG + 2097152;
    float* S1  = S0 + BSD;
    float* S2  = S1 + BSD;
    float* S3  = S2 + BSD;
    float* S4  = S3 + BSD;

    float* xn       = S0;   // 1-2
    float* q        = S1;   // 2-3  (q,k,v contiguous S1,S2,S3 for z-batched QKV)
    float* v_       = S3;
    float* attn     = BIG;  // 3-4
    float* ctx      = S4;   // 3-5
    float* attn_out = S0;   // 5-6
    float* hidden   = BIG;  // 6-7
    float* nu       = S2;   // 7-13 (zeroed after attn; split-K atomic target)
    float* a_part   = S0;   // 8-9  (a_part,b_part contiguous S0,S1 for z-batched rc)
    float* Mbuf     = BIG;  // 10-11
    float* agg      = S1;   // 11-12 (zeroed after edge; split-K atomic target)
    float* y        = S0;   // 13-14

    // 1. LN1
    hipLaunchKernelGGL(ln1_kernel, dim3(BS), dim3(256), 0, stream, x, ln1_g, ln1_b, xn);
    // 2. QKV: z-batched, outputs S1,S2,S3
    hipLaunchKernelGGL(gemm64_zw_kernel, dim3(D_ / TS, BS / TS, 3), dim3(256), 0, stream,
                       xn, wq, wk, wv, bq, bk, bv, q, BS, D_, D_);
    // 3. attention -> attn(BIG), ctx(S4)
    hipLaunchKernelGGL(attn_kernel, dim3(B_ * H_ * S_), dim3(S_), 0, stream,
                       q, q + BSD, v_, attn, ctx);
    // zero nu (S2) now that k is dead (before FFN2's atomics)
    hipMemsetAsync(nu, 0, (size_t)BSD * 4, stream);
    // 4. adjacency
    hipLaunchKernelGGL(adj_kernel, dim3(B_ * S_ * S_ / 256), dim3(256), 0, stream, attn, adj);
    // 5. wo projection: ctx -> attn_out(S0)
    hipLaunchKernelGGL(gemm64_kernel, dim3(D_ / TS, BS / TS), dim3(256), 0, stream,
                       ctx, wo, bo, attn_out, D_, D_, 0);
    // 6. FFN1 (relu): attn_out -> hidden(BIG)
    hipLaunchKernelGGL(gemm64_kernel, dim3(F_ / TS, BS / TS), dim3(256), 0, stream,
                       attn_out, w1, b1, hidden, F_, D_, 1);
    // 7. FFN2 split-K=4 (atomic into zeroed nu, bias at z==0)
    hipLaunchKernelGGL(gemm64_sk_kernel, dim3(D_ / TS, BS / TS, 4), dim3(256), 0, stream,
                       hidden, w2, b2, nu, D_, F_);
    // 8. rc halves: z-batched, weights rc_w1 + z*D*D, outputs S0,S1
    hipLaunchKernelGGL(gemm64_zw_kernel, dim3(D_ / TS, BS / TS, 2), dim3(256), 0, stream,
                       nu, rc_w1, rc_w1 + D_ * D_, (const float*)nullptr,
                       (const float*)nullptr, (const float*)nullptr, (const float*)nullptr,
                       a_part, BS, D_, D_);
    // 9. edges -> rel
    hipLaunchKernelGGL(edge_kernel, dim3(B_ * S_ * S_), dim3(64), 0, stream,
                       a_part, a_part + BSD, rc_b1, rc_w2, rc_b2, adj, rel);
    // zero agg (S1) now that b_part is dead
    hipMemsetAsync(agg, 0, (size_t)BSD * 4, stream);
    // 10. RGCN aggregate: nu, rel -> Mbuf(BIG)
    hipLaunchKernelGGL(mbuild_kernel, dim3(BS), dim3(128), 0, stream, nu, rel, Mbuf);
    // 11. Mbuf @ kg_w, split-K=8 (atomic into zeroed agg)
    hipLaunchKernelGGL(gemm64_sk_kernel, dim3(D_ / TS, BS / TS, 8), dim3(256), 0, stream,
                       Mbuf, kg_w, (const float*)nullptr, agg, D_, R_ * D_);
    // 12. reasoned = nu + agg
    hipLaunchKernelGGL(add_kernel, dim3(BSD / 256), dim3(256), 0, stream, nu, agg, BSD);
    // 13. s2n: nu -> y(S0)
    hipLaunchKernelGGL(gemm64_kernel, dim3(D_ / TS, BS / TS), dim3(256), 0, stream,
                       nu, s2n_w, s2n_b, y, D_, D_, 0);
    // 14. LN2 -> out (fp32)
    hipLaunchKernelGGL(ln2_kernel, dim3(BS), dim3(256), 0, stream, x, y, ln2_g, ln2_b, out);
}

// Round 7
// 319.128 us; speedup vs baseline: 1.8725x; 1.3034x over previous
//
#include <hip/hip_runtime.h>
#include <hip/hip_bf16.h>

#define B_ 4
#define S_ 128
#define D_ 512
#define H_ 8
#define DH_ 64
#define F_ 2048
#define R_ 8

typedef __attribute__((ext_vector_type(8))) short short8;
typedef __attribute__((ext_vector_type(4))) float f32x4;

// fp32 -> bf16 hi (RNE) + bf16 lo (RNE of exact residual)
__device__ __forceinline__ void split2(float a, unsigned short& h, unsigned short& l) {
    unsigned u = __float_as_uint(a);
    unsigned hr = (u + 0x7FFFu + ((u >> 16) & 1u)) >> 16;
    h = (unsigned short)hr;
    float lo = a - __uint_as_float(hr << 16);
    unsigned u2 = __float_as_uint(lo);
    l = (unsigned short)((u2 + 0x7FFFu + ((u2 >> 16) & 1u)) >> 16);
}

// ---------------- weight transpose + bf16 hi/lo split ----------------
struct TDesc { const float* s; unsigned short* h; unsigned short* l; int K; int N; int off; };
struct TPack { TDesc d[10]; };

__global__ void transpose_split_kernel(TPack p) {
    __shared__ float sm[32][33];
    int bid = blockIdx.x;
    int wi = 0;
#pragma unroll
    for (int i = 1; i < 10; ++i) if (bid >= p.d[i].off) wi = i;
    const TDesc dd = p.d[wi];
    int t = bid - dd.off;
    int ntk = dd.K / 32;
    int tk = t % ntk, tn = t / ntk;
    int k0 = tk * 32, n0 = tn * 32;
    int col = threadIdx.x & 31, rg = threadIdx.x >> 5;   // rg 0..7
#pragma unroll
    for (int i = 0; i < 4; ++i) {
        int row = rg * 4 + i;
        sm[row][col] = dd.s[(size_t)(k0 + row) * dd.N + n0 + col];
    }
    __syncthreads();
#pragma unroll
    for (int i = 0; i < 4; ++i) {
        int n = n0 + rg * 4 + i;
        int k = k0 + col;
        float v = sm[col][rg * 4 + i];
        unsigned short h, l;
        split2(v, h, l);
        dd.h[(size_t)n * dd.K + k] = h;
        dd.l[(size_t)n * dd.K + k] = l;
    }
}

// ---------------- MFMA bf16x3 GEMM core ----------------
// C[M,N] = A[M,K](f32) @ B[K,N] with B given transposed+split: Bth/Btl [N][K] bf16.
// Block: 256 thr = 4 waves; tile 64x64; wave 32x32 (2x2 of 16x16x32 MFMA); BK=32.
#define RP 40   // LDS row pitch in ushorts (32 + 8 pad) = 80 B

__device__ __forceinline__ void mgemm_core(const float* __restrict__ A,
                                           const unsigned short* __restrict__ Bth,
                                           const unsigned short* __restrict__ Btl,
                                           int K, int rowBase, int colBase,
                                           int kStart, int kLen,
                                           f32x4 acc[2][2],
                                           unsigned short Ah[64][RP], unsigned short Al[64][RP],
                                           unsigned short Bh[64][RP], unsigned short Bl[64][RP]) {
    int tid = threadIdx.x;
    int w = tid >> 6, lane = tid & 63;
    int lm = lane & 15, quad = lane >> 4;
    int wm = (w & 1) * 32, wn = (w >> 1) * 32;
    int rA = tid >> 3, kcA = tid & 7;          // A task 0: row, float4-chunk
    int rB = tid >> 2, kcB = tid & 3;          // B task: row, short8-chunk
    for (int k0 = kStart; k0 < kStart + kLen; k0 += 32) {
        // stage A (fp32 -> hi/lo bf16), 2 tasks/thread
#pragma unroll
        for (int i = 0; i < 2; ++i) {
            int r = rA + i * 32;
            const float4 av = *(const float4*)&A[(size_t)(rowBase + r) * K + k0 + kcA * 4];
            unsigned short h[4], l[4];
            split2(av.x, h[0], l[0]); split2(av.y, h[1], l[1]);
            split2(av.z, h[2], l[2]); split2(av.w, h[3], l[3]);
            unsigned long long ph = (unsigned long long)h[0] | ((unsigned long long)h[1] << 16)
                                  | ((unsigned long long)h[2] << 32) | ((unsigned long long)h[3] << 48);
            unsigned long long pl = (unsigned long long)l[0] | ((unsigned long long)l[1] << 16)
                                  | ((unsigned long long)l[2] << 32) | ((unsigned long long)l[3] << 48);
            *(unsigned long long*)&Ah[r][kcA * 4] = ph;
            *(unsigned long long*)&Al[r][kcA * 4] = pl;
        }
        // stage B (already bf16 hi/lo, k-contiguous)
        {
            const short8 bvh = *(const short8*)&Bth[(size_t)(colBase + rB) * K + k0 + kcB * 8];
            *(short8*)&Bh[rB][kcB * 8] = bvh;
            const short8 bvl = *(const short8*)&Btl[(size_t)(colBase + rB) * K + k0 + kcB * 8];
            *(short8*)&Bl[rB][kcB * 8] = bvl;
        }
        __syncthreads();
        short8 ah[2], al[2], bh[2], bl[2];
#pragma unroll
        for (int t = 0; t < 2; ++t) {
            ah[t] = *(const short8*)&Ah[wm + t * 16 + lm][quad * 8];
            al[t] = *(const short8*)&Al[wm + t * 16 + lm][quad * 8];
            bh[t] = *(const short8*)&Bh[wn + t * 16 + lm][quad * 8];
            bl[t] = *(const short8*)&Bl[wn + t * 16 + lm][quad * 8];
        }
#pragma unroll
        for (int tm = 0; tm < 2; ++tm)
#pragma unroll
            for (int tn = 0; tn < 2; ++tn) {
                acc[tm][tn] = __builtin_amdgcn_mfma_f32_16x16x32_bf16(ah[tm], bh[tn], acc[tm][tn], 0, 0, 0);
                acc[tm][tn] = __builtin_amdgcn_mfma_f32_16x16x32_bf16(ah[tm], bl[tn], acc[tm][tn], 0, 0, 0);
                acc[tm][tn] = __builtin_amdgcn_mfma_f32_16x16x32_bf16(al[tm], bh[tn], acc[tm][tn], 0, 0, 0);
            }
        __syncthreads();
    }
}

// plain: C = A@B + bias, opt relu. grid (N/64, M/64)
__global__ __launch_bounds__(256) void mgemm_kernel(const float* __restrict__ A,
                                                    const unsigned short* __restrict__ Bth,
                                                    const unsigned short* __restrict__ Btl,
                                                    const float* __restrict__ bias,
                                                    float* __restrict__ C,
                                                    int N, int K, int relu) {
    __shared__ unsigned short Ah[64][RP], Al[64][RP], Bh[64][RP], Bl[64][RP];
    int tid = threadIdx.x;
    int w = tid >> 6, lane = tid & 63;
    int lm = lane & 15, quad = lane >> 4;
    int wm = (w & 1) * 32, wn = (w >> 1) * 32;
    int rowBase = blockIdx.y * 64, colBase = blockIdx.x * 64;
    f32x4 acc[2][2] = {};
    mgemm_core(A, Bth, Btl, K, rowBase, colBase, 0, K, acc, Ah, Al, Bh, Bl);
#pragma unroll
    for (int tm = 0; tm < 2; ++tm)
#pragma unroll
        for (int tn = 0; tn < 2; ++tn) {
            int col = colBase + wn + tn * 16 + lm;
            float bi = bias ? bias[col] : 0.f;
#pragma unroll
            for (int r = 0; r < 4; ++r) {
                int row = rowBase + wm + tm * 16 + quad * 4 + r;
                float v = acc[tm][tn][r] + bi;
                if (relu) v = fmaxf(v, 0.f);
                C[(size_t)row * N + col] = v;
            }
        }
}

// z-batched weights (stride K*N in Bt arrays), outputs stride M*N. N = D here.
__global__ __launch_bounds__(256) void mgemm_zw_kernel(const float* __restrict__ A,
                                                       const unsigned short* __restrict__ Bth,
                                                       const unsigned short* __restrict__ Btl,
                                                       const float* __restrict__ b0,
                                                       const float* __restrict__ b1,
                                                       const float* __restrict__ b2,
                                                       float* __restrict__ Cbase,
                                                       int M, int N, int K) {
    __shared__ unsigned short Ah[64][RP], Al[64][RP], Bh[64][RP], Bl[64][RP];
    int z = blockIdx.z;
    const unsigned short* bth = Bth + (size_t)z * K * N;
    const unsigned short* btl = Btl + (size_t)z * K * N;
    const float* bias = (z == 0) ? b0 : (z == 1) ? b1 : b2;
    float* C = Cbase + (size_t)z * M * N;
    int tid = threadIdx.x;
    int w = tid >> 6, lane = tid & 63;
    int lm = lane & 15, quad = lane >> 4;
    int wm = (w & 1) * 32, wn = (w >> 1) * 32;
    int rowBase = blockIdx.y * 64, colBase = blockIdx.x * 64;
    f32x4 acc[2][2] = {};
    mgemm_core(A, bth, btl, K, rowBase, colBase, 0, K, acc, Ah, Al, Bh, Bl);
#pragma unroll
    for (int tm = 0; tm < 2; ++tm)
#pragma unroll
        for (int tn = 0; tn < 2; ++tn) {
            int col = colBase + wn + tn * 16 + lm;
            float bi = bias ? bias[col] : 0.f;
#pragma unroll
            for (int r = 0; r < 4; ++r) {
                int row = rowBase + wm + tm * 16 + quad * 4 + r;
                C[(size_t)row * N + col] = acc[tm][tn][r] + bi;
            }
        }
}

// split-K: grid.z = ksplit; C pre-zeroed; atomicAdd partials; bias at z==0.
__global__ __launch_bounds__(256) void mgemm_sk_kernel(const float* __restrict__ A,
                                                       const unsigned short* __restrict__ Bth,
                                                       const unsigned short* __restrict__ Btl,
                                                       const float* __restrict__ bias,
                                                       float* __restrict__ C,
                                                       int N, int K) {
    __shared__ unsigned short Ah[64][RP], Al[64][RP], Bh[64][RP], Bl[64][RP];
    int ks = gridDim.z, z = blockIdx.z;
    int kLen = K / ks, kStart = z * kLen;
    int tid = threadIdx.x;
    int w = tid >> 6, lane = tid & 63;
    int lm = lane & 15, quad = lane >> 4;
    int wm = (w & 1) * 32, wn = (w >> 1) * 32;
    int rowBase = blockIdx.y * 64, colBase = blockIdx.x * 64;
    f32x4 acc[2][2] = {};
    mgemm_core(A, Bth, Btl, K, rowBase, colBase, kStart, kLen, acc, Ah, Al, Bh, Bl);
#pragma unroll
    for (int tm = 0; tm < 2; ++tm)
#pragma unroll
        for (int tn = 0; tn < 2; ++tn) {
            int col = colBase + wn + tn * 16 + lm;
            float bi = (bias && z == 0) ? bias[col] : 0.f;
#pragma unroll
            for (int r = 0; r < 4; ++r) {
                int row = rowBase + wm + tm * 16 + quad * 4 + r;
                atomicAdd(&C[(size_t)row * N + col], acc[tm][tn][r] + bi);
            }
        }
}

// ---------------- LayerNorm 1 ----------------
__global__ void ln1_kernel(const float* __restrict__ x, const float* __restrict__ g,
                           const float* __restrict__ be, float* __restrict__ xn) {
    int row = blockIdx.x;
    int t = threadIdx.x;
    __shared__ float red[256];
    const float* xr = x + row * D_;
    float v0 = xr[t];
    float v1 = xr[t + 256];
    red[t] = v0 + v1;
    __syncthreads();
    for (int off = 128; off > 0; off >>= 1) {
        if (t < off) red[t] += red[t + off];
        __syncthreads();
    }
    float mean = red[0] * (1.0f / D_);
    __syncthreads();
    float d0 = v0 - mean, d1 = v1 - mean;
    red[t] = d0 * d0 + d1 * d1;
    __syncthreads();
    for (int off = 128; off > 0; off >>= 1) {
        if (t < off) red[t] += red[t + off];
        __syncthreads();
    }
    float rs = rsqrtf(red[0] * (1.0f / D_) + 1e-5f);
    float* o = xn + row * D_;
    o[t]       = d0 * rs * g[t]       + be[t];
    o[t + 256] = d1 * rs * g[t + 256] + be[t + 256];
}

// ---------------- Attention ----------------
__global__ void attn_kernel(const float* __restrict__ q, const float* __restrict__ k,
                            const float* __restrict__ v, float* __restrict__ attn,
                            float* __restrict__ ctx) {
    int blk = blockIdx.x;
    int i = blk % S_;
    int bh = blk / S_;
    int h = bh % H_;
    int b = bh / H_;
    int t = threadIdx.x;
    __shared__ float qs[DH_];
    __shared__ float sc[S_];
    __shared__ float red[S_];
    if (t < DH_) qs[t] = q[(b * S_ + i) * D_ + h * DH_ + t];
    __syncthreads();
    {
        const float* krow = k + (b * S_ + t) * D_ + h * DH_;
        float acc = 0.f;
#pragma unroll 8
        for (int d = 0; d < DH_; ++d) acc += qs[d] * krow[d];
        sc[t] = acc * 0.125f;
    }
    __syncthreads();
    red[t] = sc[t];
    __syncthreads();
    for (int off = 64; off > 0; off >>= 1) {
        if (t < off) red[t] = fmaxf(red[t], red[t + off]);
        __syncthreads();
    }
    float mx = red[0];
    __syncthreads();
    float e = expf(sc[t] - mx);
    red[t] = e;
    __syncthreads();
    for (int off = 64; off > 0; off >>= 1) {
        if (t < off) red[t] += red[t + off];
        __syncthreads();
    }
    float p = e / red[0];
    __syncthreads();
    sc[t] = p;
    attn[((b * H_ + h) * (long)S_ + i) * S_ + t] = p;
    __syncthreads();
    if (t < DH_) {
        const float* vbase = v + b * S_ * D_ + h * DH_ + t;
        float acc = 0.f;
        for (int j = 0; j < S_; ++j) acc += sc[j] * vbase[j * D_];
        ctx[(b * S_ + i) * D_ + h * DH_ + t] = acc;
    }
}

// ---------------- Adjacency ----------------
__global__ void adj_kernel(const float* __restrict__ attn, int* __restrict__ adj) {
    int idx = blockIdx.x * 256 + threadIdx.x;
    if (idx >= B_ * S_ * S_) return;
    int j = idx % S_;
    int bi = idx / S_;
    int i = bi % S_;
    int b = bi / S_;
    float s = 0.f;
#pragma unroll
    for (int h = 0; h < H_; ++h) s += attn[((b * H_ + h) * (long)S_ + i) * S_ + j];
    s *= (1.0f / H_);
    adj[idx] = (s > 0.1f && i != j) ? 1 : 0;
}

// ---------------- Relation classifier at edges ----------------
__global__ void edge_kernel(const float* __restrict__ a_part, const float* __restrict__ b_part,
                            const float* __restrict__ rc_b1, const float* __restrict__ rc_w2,
                            const float* __restrict__ rc_b2, const int* __restrict__ adj,
                            int* __restrict__ rel) {
    int blk = blockIdx.x;
    int lane = threadIdx.x;
    if (adj[blk] == 0) {
        if (lane == 0) rel[blk] = 0;
        return;
    }
    __shared__ float sred[64][R_ + 1];
    __shared__ float logit[R_];
    int vv = blk % S_;
    int bu = blk / S_;
    int u = bu % S_;
    int b = bu / S_;
    const float* ap = a_part + (b * S_ + u) * D_;
    const float* bp = b_part + (b * S_ + vv) * D_;
    float lp[R_];
#pragma unroll
    for (int r = 0; r < R_; ++r) lp[r] = 0.f;
    for (int jj = 0; jj < D_ / 64; ++jj) {
        int d = lane + jj * 64;
        float hv = fmaxf(ap[d] + bp[d] + rc_b1[d], 0.f);
#pragma unroll
        for (int r = 0; r < R_; ++r) lp[r] += hv * rc_w2[d * R_ + r];
    }
#pragma unroll
    for (int r = 0; r < R_; ++r) sred[lane][r] = lp[r];
    __syncthreads();
    if (lane < R_) {
        float tot = rc_b2[lane];
        for (int i = 0; i < 64; ++i) tot += sred[i][lane];
        logit[lane] = tot;
    }
    __syncthreads();
    if (lane == 0) {
        float best = logit[0];
        int bi = 0;
#pragma unroll
        for (int r = 1; r < R_; ++r) {
            if (logit[r] > best) { best = logit[r]; bi = r; }
        }
        rel[blk] = bi;
    }
}

// ---------------- M[b,v, r*D+d] = sum_u [rel(u,v)==r] nu[b,u,d] ----------------
__global__ void mbuild_kernel(const float* __restrict__ nu, const int* __restrict__ rel,
                              float* __restrict__ M) {
    int blk = blockIdx.x;
    int vv = blk % S_;
    int b = blk / S_;
    int t = threadIdx.x;
    float* Mrow = M + (long)blk * (R_ * D_);
    for (int i = t; i < R_ * D_; i += 128) Mrow[i] = 0.f;
    __syncthreads();
    const int* relbase = rel + (long)b * S_ * S_ + vv;
    for (int u = 0; u < S_; ++u) {
        int r = relbase[u * S_];
        if (r >= 1 && r < R_) {
            const float* nurow = nu + (b * S_ + u) * D_;
            for (int d = t; d < D_; d += 128) Mrow[r * D_ + d] += nurow[d];
        }
    }
}

// ---------------- nu += agg ----------------
__global__ void add_kernel(float* __restrict__ nu, const float* __restrict__ agg, int n) {
    int i = blockIdx.x * 256 + threadIdx.x;
    if (i < n) nu[i] += agg[i];
}

// ---------------- LayerNorm 2 -> fp32 out ----------------
__global__ void ln2_kernel(const float* __restrict__ x, const float* __restrict__ y,
                           const float* __restrict__ g, const float* __restrict__ be,
                           float* __restrict__ out) {
    int row = blockIdx.x;
    int t = threadIdx.x;
    __shared__ float red[256];
    float v0 = x[row * D_ + t]       + y[row * D_ + t];
    float v1 = x[row * D_ + t + 256] + y[row * D_ + t + 256];
    red[t] = v0 + v1;
    __syncthreads();
    for (int off = 128; off > 0; off >>= 1) {
        if (t < off) red[t] += red[t + off];
        __syncthreads();
    }
    float mean = red[0] * (1.0f / D_);
    __syncthreads();
    float d0 = v0 - mean, d1 = v1 - mean;
    red[t] = d0 * d0 + d1 * d1;
    __syncthreads();
    for (int off = 128; off > 0; off >>= 1) {
        if (t < off) red[t] += red[t + off];
        __syncthreads();
    }
    float rs = rsqrtf(red[0] * (1.0f / D_) + 1e-5f);
    out[row * D_ + t]       = d0 * rs * g[t]       + be[t];
    out[row * D_ + t + 256] = d1 * rs * g[t + 256] + be[t + 256];
}

extern "C" void kernel_launch(void* const* d_in, const int* in_sizes, int n_in,
                              void* d_out, int out_size, void* d_ws, size_t ws_size,
                              hipStream_t stream) {
    const float* x     = (const float*)d_in[0];
    const float* ln1_g = (const float*)d_in[1];
    const float* ln1_b = (const float*)d_in[2];
    const float* wq    = (const float*)d_in[3];
    const float* bq    = (const float*)d_in[4];
    const float* wk    = (const float*)d_in[5];
    const float* bk    = (const float*)d_in[6];
    const float* wv    = (const float*)d_in[7];
    const float* bv    = (const float*)d_in[8];
    const float* wo    = (const float*)d_in[9];
    const float* bo    = (const float*)d_in[10];
    const float* w1    = (const float*)d_in[11];
    const float* b1    = (const float*)d_in[12];
    const float* w2    = (const float*)d_in[13];
    const float* b2    = (const float*)d_in[14];
    const float* rc_w1 = (const float*)d_in[15];
    const float* rc_b1 = (const float*)d_in[16];
    const float* rc_w2 = (const float*)d_in[17];
    const float* rc_b2 = (const float*)d_in[18];
    const float* kg_w  = (const float*)d_in[19];
    const float* s2n_w = (const float*)d_in[20];
    const float* s2n_b = (const float*)d_in[21];
    const float* ln2_g = (const float*)d_in[22];
    const float* ln2_b = (const float*)d_in[23];
    float* out = (float*)d_out;

    const int BS  = B_ * S_;          // 512
    const int BSD = BS * D_;          // 262144

    // ---- Workspace layout ----
    // WT (transposed bf16 hi/lo weights): 12,058,624 ushorts = 24.1 MB
    unsigned short* wt = (unsigned short*)d_ws;
    const size_t E = 262144;          // 512*512
    unsigned short* qkv_h = wt;                       // 3E
    unsigned short* qkv_l = wt + 3 * E;               // 3E
    unsigned short* wo_h  = wt + 6 * E;
    unsigned short* wo_l  = wt + 7 * E;
    unsigned short* w1_h  = wt + 8 * E;               // 4E (512x2048)
    unsigned short* w1_l  = wt + 12 * E;
    unsigned short* w2_h  = wt + 16 * E;              // 4E (2048x512)
    unsigned short* w2_l  = wt + 20 * E;
    unsigned short* rc_h  = wt + 24 * E;              // 2E
    unsigned short* rc_l  = wt + 26 * E;
    unsigned short* kg_h  = wt + 28 * E;              // 8E (4096x512 -> 512x4096)
    unsigned short* kg_l  = wt + 36 * E;
    unsigned short* s2_h  = wt + 44 * E;
    unsigned short* s2_l  = wt + 45 * E;
    size_t wt_words = 46 * E;                          // ushorts

    int* adj   = (int*)(wt + wt_words);
    int* rel   = adj + B_ * S_ * S_;
    float* BIG = (float*)(rel + B_ * S_ * S_);         // 2,097,152 floats
    float* S0  = BIG + 2097152;
    float* S1  = S0 + BSD;
    float* S2  = S1 + BSD;
    float* S3  = S2 + BSD;
    float* S4  = S3 + BSD;

    float* xn       = S0;
    float* q        = S1;   // q,k,v contiguous S1,S2,S3
    float* v_       = S3;
    float* attn     = BIG;
    float* ctx      = S4;
    float* attn_out = S0;
    float* hidden   = BIG;
    float* nu       = S2;
    float* a_part   = S0;   // a_part,b_part contiguous S0,S1
    float* Mbuf     = BIG;
    float* agg      = S1;
    float* y        = S0;

    // 0. transpose+split all weights (tiles: 256 each for 512x512; 1024 for w1/w2; 2048 for kg)
    TPack tp;
    int off = 0;
    auto setd = [&](int i, const float* s, unsigned short* h, unsigned short* l, int K, int N) {
        tp.d[i] = TDesc{s, h, l, K, N, off};
        off += (K / 32) * (N / 32);
    };
    setd(0, wq, qkv_h,         qkv_l,         D_, D_);
    setd(1, wk, qkv_h + E,     qkv_l + E,     D_, D_);
    setd(2, wv, qkv_h + 2 * E, qkv_l + 2 * E, D_, D_);
    setd(3, wo, wo_h, wo_l, D_, D_);
    setd(4, w1, w1_h, w1_l, D_, F_);
    setd(5, w2, w2_h, w2_l, F_, D_);
    setd(6, rc_w1,            rc_h,     rc_l,     D_, D_);
    setd(7, rc_w1 + D_ * D_,  rc_h + E, rc_l + E, D_, D_);
    setd(8, kg_w, kg_h, kg_l, R_ * D_, D_);
    setd(9, s2n_w, s2_h, s2_l, D_, D_);
    hipLaunchKernelGGL(transpose_split_kernel, dim3(off), dim3(256), 0, stream, tp);

    // 1. LN1
    hipLaunchKernelGGL(ln1_kernel, dim3(BS), dim3(256), 0, stream, x, ln1_g, ln1_b, xn);
    // 2. QKV (z-batched) -> S1,S2,S3
    hipLaunchKernelGGL(mgemm_zw_kernel, dim3(D_ / 64, BS / 64, 3), dim3(256), 0, stream,
                       xn, qkv_h, qkv_l, bq, bk, bv, q, BS, D_, D_);
    // 3. attention -> attn(BIG), ctx(S4)
    hipLaunchKernelGGL(attn_kernel, dim3(B_ * H_ * S_), dim3(S_), 0, stream,
                       q, q + BSD, v_, attn, ctx);
    hipMemsetAsync(nu, 0, (size_t)BSD * 4, stream);   // k dead; FFN2 atomic target
    // 4. adjacency
    hipLaunchKernelGGL(adj_kernel, dim3(B_ * S_ * S_ / 256), dim3(256), 0, stream, attn, adj);
    // 5. wo: ctx -> attn_out
    hipLaunchKernelGGL(mgemm_kernel, dim3(D_ / 64, BS / 64), dim3(256), 0, stream,
                       ctx, wo_h, wo_l, bo, attn_out, D_, D_, 0);
    // 6. FFN1 (relu): attn_out -> hidden
    hipLaunchKernelGGL(mgemm_kernel, dim3(F_ / 64, BS / 64), dim3(256), 0, stream,
                       attn_out, w1_h, w1_l, b1, hidden, F_, D_, 1);
    // 7. FFN2 split-K=4 -> nu
    hipLaunchKernelGGL(mgemm_sk_kernel, dim3(D_ / 64, BS / 64, 4), dim3(256), 0, stream,
                       hidden, w2_h, w2_l, b2, nu, D_, F_);
    // 8. rc halves (z-batched) -> a_part,b_part
    hipLaunchKernelGGL(mgemm_zw_kernel, dim3(D_ / 64, BS / 64, 2), dim3(256), 0, stream,
                       nu, rc_h, rc_l, (const float*)nullptr, (const float*)nullptr,
                       (const float*)nullptr, a_part, BS, D_, D_);
    // 9. edges
    hipLaunchKernelGGL(edge_kernel, dim3(B_ * S_ * S_), dim3(64), 0, stream,
                       a_part, a_part + BSD, rc_b1, rc_w2, rc_b2, adj, rel);
    hipMemsetAsync(agg, 0, (size_t)BSD * 4, stream);  // b_part dead; agg atomic target
    // 10. RGCN aggregate
    hipLaunchKernelGGL(mbuild_kernel, dim3(BS), dim3(128), 0, stream, nu, rel, Mbuf);
    // 11. Mbuf @ kg_w split-K=8 -> agg
    hipLaunchKernelGGL(mgemm_sk_kernel, dim3(D_ / 64, BS / 64, 8), dim3(256), 0, stream,
                       Mbuf, kg_h, kg_l, (const float*)nullptr, agg, D_, R_ * D_);
    // 12. nu += agg
    hipLaunchKernelGGL(add_kernel, dim3(BSD / 256), dim3(256), 0, stream, nu, agg, BSD);
    // 13. s2n: nu -> y
    hipLaunchKernelGGL(mgemm_kernel, dim3(D_ / 64, BS / 64), dim3(256), 0, stream,
                       nu, s2_h, s2_l, s2n_b, y, D_, D_, 0);
    // 14. LN2 -> out
    hipLaunchKernelGGL(ln2_kernel, dim3(BS), dim3(256), 0, stream, x, y, ln2_g, ln2_b, out);
}

// Round 8
// 293.758 us; speedup vs baseline: 2.0342x; 1.0864x over previous
//
#include <hip/hip_runtime.h>
#include <hip/hip_bf16.h>

#define B_ 4
#define S_ 128
#define D_ 512
#define H_ 8
#define DH_ 64
#define F_ 2048
#define R_ 8

typedef __attribute__((ext_vector_type(8))) short short8;
typedef __attribute__((ext_vector_type(4))) float f32x4;

// fp32 -> bf16 hi (RNE) + bf16 lo (RNE of exact residual)
__device__ __forceinline__ void split2(float a, unsigned short& h, unsigned short& l) {
    unsigned u = __float_as_uint(a);
    unsigned hr = (u + 0x7FFFu + ((u >> 16) & 1u)) >> 16;
    h = (unsigned short)hr;
    float lo = a - __uint_as_float(hr << 16);
    unsigned u2 = __float_as_uint(lo);
    l = (unsigned short)((u2 + 0x7FFFu + ((u2 >> 16) & 1u)) >> 16);
}

// ---------------- weight transpose + bf16 hi/lo split ----------------
struct TDesc { const float* s; unsigned short* h; unsigned short* l; int K; int N; int off; };
struct TPack { TDesc d[10]; };

__global__ void transpose_split_kernel(TPack p) {
    __shared__ float sm[32][33];
    int bid = blockIdx.x;
    int wi = 0;
#pragma unroll
    for (int i = 1; i < 10; ++i) if (bid >= p.d[i].off) wi = i;
    const TDesc dd = p.d[wi];
    int t = bid - dd.off;
    int ntk = dd.K / 32;
    int tk = t % ntk, tn = t / ntk;
    int k0 = tk * 32, n0 = tn * 32;
    int col = threadIdx.x & 31, rg = threadIdx.x >> 5;   // rg 0..7
#pragma unroll
    for (int i = 0; i < 4; ++i) {
        int row = rg * 4 + i;
        sm[row][col] = dd.s[(size_t)(k0 + row) * dd.N + n0 + col];
    }
    __syncthreads();
#pragma unroll
    for (int i = 0; i < 4; ++i) {
        int n = n0 + rg * 4 + i;
        int k = k0 + col;
        float v = sm[col][rg * 4 + i];
        unsigned short h, l;
        split2(v, h, l);
        dd.h[(size_t)n * dd.K + k] = h;
        dd.l[(size_t)n * dd.K + k] = l;
    }
}

// ---------------- MFMA bf16x3 GEMM core ----------------
#define RP 40   // LDS row pitch in ushorts (32 + 8 pad)

__device__ __forceinline__ void mgemm_core(const float* __restrict__ A,
                                           const unsigned short* __restrict__ Bth,
                                           const unsigned short* __restrict__ Btl,
                                           int K, int rowBase, int colBase,
                                           int kStart, int kLen,
                                           f32x4 acc[2][2],
                                           unsigned short Ah[64][RP], unsigned short Al[64][RP],
                                           unsigned short Bh[64][RP], unsigned short Bl[64][RP]) {
    int tid = threadIdx.x;
    int w = tid >> 6, lane = tid & 63;
    int lm = lane & 15, quad = lane >> 4;
    int wm = (w & 1) * 32, wn = (w >> 1) * 32;
    int rA = tid >> 3, kcA = tid & 7;
    int rB = tid >> 2, kcB = tid & 3;
    for (int k0 = kStart; k0 < kStart + kLen; k0 += 32) {
#pragma unroll
        for (int i = 0; i < 2; ++i) {
            int r = rA + i * 32;
            const float4 av = *(const float4*)&A[(size_t)(rowBase + r) * K + k0 + kcA * 4];
            unsigned short h[4], l[4];
            split2(av.x, h[0], l[0]); split2(av.y, h[1], l[1]);
            split2(av.z, h[2], l[2]); split2(av.w, h[3], l[3]);
            unsigned long long ph = (unsigned long long)h[0] | ((unsigned long long)h[1] << 16)
                                  | ((unsigned long long)h[2] << 32) | ((unsigned long long)h[3] << 48);
            unsigned long long pl = (unsigned long long)l[0] | ((unsigned long long)l[1] << 16)
                                  | ((unsigned long long)l[2] << 32) | ((unsigned long long)l[3] << 48);
            *(unsigned long long*)&Ah[r][kcA * 4] = ph;
            *(unsigned long long*)&Al[r][kcA * 4] = pl;
        }
        {
            const short8 bvh = *(const short8*)&Bth[(size_t)(colBase + rB) * K + k0 + kcB * 8];
            *(short8*)&Bh[rB][kcB * 8] = bvh;
            const short8 bvl = *(const short8*)&Btl[(size_t)(colBase + rB) * K + k0 + kcB * 8];
            *(short8*)&Bl[rB][kcB * 8] = bvl;
        }
        __syncthreads();
        short8 ah[2], al[2], bh[2], bl[2];
#pragma unroll
        for (int t = 0; t < 2; ++t) {
            ah[t] = *(const short8*)&Ah[wm + t * 16 + lm][quad * 8];
            al[t] = *(const short8*)&Al[wm + t * 16 + lm][quad * 8];
            bh[t] = *(const short8*)&Bh[wn + t * 16 + lm][quad * 8];
            bl[t] = *(const short8*)&Bl[wn + t * 16 + lm][quad * 8];
        }
#pragma unroll
        for (int tm = 0; tm < 2; ++tm)
#pragma unroll
            for (int tn = 0; tn < 2; ++tn) {
                acc[tm][tn] = __builtin_amdgcn_mfma_f32_16x16x32_bf16(ah[tm], bh[tn], acc[tm][tn], 0, 0, 0);
                acc[tm][tn] = __builtin_amdgcn_mfma_f32_16x16x32_bf16(ah[tm], bl[tn], acc[tm][tn], 0, 0, 0);
                acc[tm][tn] = __builtin_amdgcn_mfma_f32_16x16x32_bf16(al[tm], bh[tn], acc[tm][tn], 0, 0, 0);
            }
        __syncthreads();
    }
}

__global__ __launch_bounds__(256) void mgemm_kernel(const float* __restrict__ A,
                                                    const unsigned short* __restrict__ Bth,
                                                    const unsigned short* __restrict__ Btl,
                                                    const float* __restrict__ bias,
                                                    float* __restrict__ C,
                                                    int N, int K, int relu) {
    __shared__ unsigned short Ah[64][RP], Al[64][RP], Bh[64][RP], Bl[64][RP];
    int tid = threadIdx.x;
    int w = tid >> 6, lane = tid & 63;
    int lm = lane & 15, quad = lane >> 4;
    int wm = (w & 1) * 32, wn = (w >> 1) * 32;
    int rowBase = blockIdx.y * 64, colBase = blockIdx.x * 64;
    f32x4 acc[2][2] = {};
    mgemm_core(A, Bth, Btl, K, rowBase, colBase, 0, K, acc, Ah, Al, Bh, Bl);
#pragma unroll
    for (int tm = 0; tm < 2; ++tm)
#pragma unroll
        for (int tn = 0; tn < 2; ++tn) {
            int col = colBase + wn + tn * 16 + lm;
            float bi = bias ? bias[col] : 0.f;
#pragma unroll
            for (int r = 0; r < 4; ++r) {
                int row = rowBase + wm + tm * 16 + quad * 4 + r;
                float v = acc[tm][tn][r] + bi;
                if (relu) v = fmaxf(v, 0.f);
                C[(size_t)row * N + col] = v;
            }
        }
}

__global__ __launch_bounds__(256) void mgemm_zw_kernel(const float* __restrict__ A,
                                                       const unsigned short* __restrict__ Bth,
                                                       const unsigned short* __restrict__ Btl,
                                                       const float* __restrict__ b0,
                                                       const float* __restrict__ b1,
                                                       const float* __restrict__ b2,
                                                       float* __restrict__ Cbase,
                                                       int M, int N, int K) {
    __shared__ unsigned short Ah[64][RP], Al[64][RP], Bh[64][RP], Bl[64][RP];
    int z = blockIdx.z;
    const unsigned short* bth = Bth + (size_t)z * K * N;
    const unsigned short* btl = Btl + (size_t)z * K * N;
    const float* bias = (z == 0) ? b0 : (z == 1) ? b1 : b2;
    float* C = Cbase + (size_t)z * M * N;
    int tid = threadIdx.x;
    int w = tid >> 6, lane = tid & 63;
    int lm = lane & 15, quad = lane >> 4;
    int wm = (w & 1) * 32, wn = (w >> 1) * 32;
    int rowBase = blockIdx.y * 64, colBase = blockIdx.x * 64;
    f32x4 acc[2][2] = {};
    mgemm_core(A, bth, btl, K, rowBase, colBase, 0, K, acc, Ah, Al, Bh, Bl);
#pragma unroll
    for (int tm = 0; tm < 2; ++tm)
#pragma unroll
        for (int tn = 0; tn < 2; ++tn) {
            int col = colBase + wn + tn * 16 + lm;
            float bi = bias ? bias[col] : 0.f;
#pragma unroll
            for (int r = 0; r < 4; ++r) {
                int row = rowBase + wm + tm * 16 + quad * 4 + r;
                C[(size_t)row * N + col] = acc[tm][tn][r] + bi;
            }
        }
}

// split-K: atomicAdd partials into C (caller ensures C holds the right base values).
__global__ __launch_bounds__(256) void mgemm_sk_kernel(const float* __restrict__ A,
                                                       const unsigned short* __restrict__ Bth,
                                                       const unsigned short* __restrict__ Btl,
                                                       const float* __restrict__ bias,
                                                       float* __restrict__ C,
                                                       int N, int K) {
    __shared__ unsigned short Ah[64][RP], Al[64][RP], Bh[64][RP], Bl[64][RP];
    int ks = gridDim.z, z = blockIdx.z;
    int kLen = K / ks, kStart = z * kLen;
    int tid = threadIdx.x;
    int w = tid >> 6, lane = tid & 63;
    int lm = lane & 15, quad = lane >> 4;
    int wm = (w & 1) * 32, wn = (w >> 1) * 32;
    int rowBase = blockIdx.y * 64, colBase = blockIdx.x * 64;
    f32x4 acc[2][2] = {};
    mgemm_core(A, Bth, Btl, K, rowBase, colBase, kStart, kLen, acc, Ah, Al, Bh, Bl);
#pragma unroll
    for (int tm = 0; tm < 2; ++tm)
#pragma unroll
        for (int tn = 0; tn < 2; ++tn) {
            int col = colBase + wn + tn * 16 + lm;
            float bi = (bias && z == 0) ? bias[col] : 0.f;
#pragma unroll
            for (int r = 0; r < 4; ++r) {
                int row = rowBase + wm + tm * 16 + quad * 4 + r;
                atomicAdd(&C[(size_t)row * N + col], acc[tm][tn][r] + bi);
            }
        }
}

// ---------------- LayerNorm 1 ----------------
__global__ void ln1_kernel(const float* __restrict__ x, const float* __restrict__ g,
                           const float* __restrict__ be, float* __restrict__ xn) {
    int row = blockIdx.x;
    int t = threadIdx.x;
    __shared__ float red[256];
    const float* xr = x + row * D_;
    float v0 = xr[t];
    float v1 = xr[t + 256];
    red[t] = v0 + v1;
    __syncthreads();
    for (int off = 128; off > 0; off >>= 1) {
        if (t < off) red[t] += red[t + off];
        __syncthreads();
    }
    float mean = red[0] * (1.0f / D_);
    __syncthreads();
    float d0 = v0 - mean, d1 = v1 - mean;
    red[t] = d0 * d0 + d1 * d1;
    __syncthreads();
    for (int off = 128; off > 0; off >>= 1) {
        if (t < off) red[t] += red[t + off];
        __syncthreads();
    }
    float rs = rsqrtf(red[0] * (1.0f / D_) + 1e-5f);
    float* o = xn + row * D_;
    o[t]       = d0 * rs * g[t]       + be[t];
    o[t + 256] = d1 * rs * g[t + 256] + be[t + 256];
}

// ---------------- Attention: one wave per (b,h,i); shuffle softmax ----------------
__global__ __launch_bounds__(256) void attn_kernel(const float* __restrict__ q,
                                                   const float* __restrict__ k,
                                                   const float* __restrict__ v,
                                                   float* __restrict__ attn,
                                                   float* __restrict__ ctx) {
    __shared__ float qsm[4][DH_];
    __shared__ float psm[4][S_];
    int w = threadIdx.x >> 6, lane = threadIdx.x & 63;
    int gid = blockIdx.x * 4 + w;         // (b*H + h)*S + i
    int i = gid & (S_ - 1);
    int bh = gid >> 7;
    int h = bh & (H_ - 1);
    int b = bh >> 3;
    const float* qrow = q + (size_t)(b * S_ + i) * D_ + h * DH_;
    qsm[w][lane] = qrow[lane & (DH_ - 1)];  // 64 lanes, 64 elems
    __syncthreads();
    // two scores per lane: j = lane, lane+64
    float s0 = 0.f, s1 = 0.f;
    const float* k0p = k + (size_t)(b * S_ + lane) * D_ + h * DH_;
    const float* k1p = k0p + (size_t)64 * D_;
#pragma unroll 8
    for (int d = 0; d < DH_; ++d) {
        float qd = qsm[w][d];
        s0 += qd * k0p[d];
        s1 += qd * k1p[d];
    }
    s0 *= 0.125f; s1 *= 0.125f;
    float m = fmaxf(s0, s1);
#pragma unroll
    for (int off = 32; off > 0; off >>= 1) m = fmaxf(m, __shfl_xor(m, off));
    float e0 = __expf(s0 - m), e1 = __expf(s1 - m);
    float sum = e0 + e1;
#pragma unroll
    for (int off = 32; off > 0; off >>= 1) sum += __shfl_xor(sum, off);
    float inv = 1.f / sum;
    float p0 = e0 * inv, p1 = e1 * inv;
    float* arow = attn + (size_t)gid * S_;
    arow[lane] = p0;
    arow[lane + 64] = p1;
    psm[w][lane] = p0;
    psm[w][lane + 64] = p1;
    __syncthreads();
    // ctx: lane = d
    const float* vbase = v + (size_t)b * S_ * D_ + h * DH_ + lane;
    float acc = 0.f;
    for (int j = 0; j < S_; ++j) acc += psm[w][j] * vbase[(size_t)j * D_];
    ctx[(size_t)(b * S_ + i) * D_ + h * DH_ + lane] = acc;
}

// ---------------- Adjacency + edge compaction ----------------
__global__ void adjc_kernel(const float* __restrict__ attn, int* __restrict__ ecount,
                            int* __restrict__ elist) {
    int idx = blockIdx.x * 256 + threadIdx.x;   // (b*S + i)*S + j
    if (idx >= B_ * S_ * S_) return;
    int j = idx & (S_ - 1);
    int bi = idx >> 7;
    int i = bi & (S_ - 1);
    int b = bi >> 7;
    float s = 0.f;
#pragma unroll
    for (int h = 0; h < H_; ++h) s += attn[(((size_t)(b * H_ + h)) * S_ + i) * S_ + j];
    s *= (1.0f / H_);
    if (s > 0.1f && i != j) {
        int p = atomicAdd(ecount, 1);
        elist[p] = idx;
    }
}

// ---------------- Relation classifier over compacted edges ----------------
__global__ __launch_bounds__(64) void edge_kernel(const float* __restrict__ a_part,
                                                  const float* __restrict__ b_part,
                                                  const float* __restrict__ rc_b1,
                                                  const float* __restrict__ rc_w2,
                                                  const float* __restrict__ rc_b2,
                                                  const int* __restrict__ elist,
                                                  const int* __restrict__ ecount,
                                                  int* __restrict__ rel) {
    int lane = threadIdx.x;
    int n = *ecount;
    for (int e = blockIdx.x; e < n; e += gridDim.x) {
        int idx = elist[e];
        int vv = idx & (S_ - 1);
        int bu = idx >> 7;
        int u = bu & (S_ - 1);
        int b = bu >> 7;
        const float* ap = a_part + (size_t)(b * S_ + u) * D_;
        const float* bp = b_part + (size_t)(b * S_ + vv) * D_;
        float lp[R_];
#pragma unroll
        for (int r = 0; r < R_; ++r) lp[r] = 0.f;
#pragma unroll
        for (int jj = 0; jj < D_ / 64; ++jj) {
            int d = lane + jj * 64;
            float hv = fmaxf(ap[d] + bp[d] + rc_b1[d], 0.f);
#pragma unroll
            for (int r = 0; r < R_; ++r) lp[r] += hv * rc_w2[d * R_ + r];
        }
#pragma unroll
        for (int r = 0; r < R_; ++r) {
#pragma unroll
            for (int off = 32; off > 0; off >>= 1) lp[r] += __shfl_down(lp[r], off);
        }
        if (lane == 0) {
            float best = lp[0] + rc_b2[0];
            int bi = 0;
#pragma unroll
            for (int r = 1; r < R_; ++r) {
                float L = lp[r] + rc_b2[r];
                if (L > best) { best = L; bi = r; }
            }
            rel[idx] = bi;
        }
    }
}

// ---------------- mbuild: LDS accumulate, single write ----------------
__global__ __launch_bounds__(128) void mbuild_kernel(const float* __restrict__ nu,
                                                     const int* __restrict__ rel,
                                                     float* __restrict__ M) {
    __shared__ float acc[R_ * D_];   // 16 KB
    __shared__ int rl[S_];
    int blk = blockIdx.x;            // b*S + v
    int vv = blk & (S_ - 1);
    int b = blk >> 7;
    int t = threadIdx.x;             // 128
    for (int i = t; i < R_ * D_; i += 128) acc[i] = 0.f;
    rl[t] = rel[((size_t)b * S_ + t) * S_ + vv];
    __syncthreads();
    for (int u = 0; u < S_; ++u) {
        int r = rl[u];
        if (r > 0) {
            const float* nurow = nu + (size_t)(b * S_ + u) * D_;
            float* arow = acc + r * D_;
#pragma unroll
            for (int jj = 0; jj < D_ / 128; ++jj) arow[t + jj * 128] += nurow[t + jj * 128];
        }
    }
    __syncthreads();
    float* Mrow = M + (size_t)blk * (R_ * D_);
    for (int i = t; i < R_ * D_; i += 128) Mrow[i] = acc[i];
}

// ---------------- LayerNorm 2 -> fp32 out ----------------
__global__ void ln2_kernel(const float* __restrict__ x, const float* __restrict__ y,
                           const float* __restrict__ g, const float* __restrict__ be,
                           float* __restrict__ out) {
    int row = blockIdx.x;
    int t = threadIdx.x;
    __shared__ float red[256];
    float v0 = x[row * D_ + t]       + y[row * D_ + t];
    float v1 = x[row * D_ + t + 256] + y[row * D_ + t + 256];
    red[t] = v0 + v1;
    __syncthreads();
    for (int off = 128; off > 0; off >>= 1) {
        if (t < off) red[t] += red[t + off];
        __syncthreads();
    }
    float mean = red[0] * (1.0f / D_);
    __syncthreads();
    float d0 = v0 - mean, d1 = v1 - mean;
    red[t] = d0 * d0 + d1 * d1;
    __syncthreads();
    for (int off = 128; off > 0; off >>= 1) {
        if (t < off) red[t] += red[t + off];
        __syncthreads();
    }
    float rs = rsqrtf(red[0] * (1.0f / D_) + 1e-5f);
    out[row * D_ + t]       = d0 * rs * g[t]       + be[t];
    out[row * D_ + t + 256] = d1 * rs * g[t + 256] + be[t + 256];
}

extern "C" void kernel_launch(void* const* d_in, const int* in_sizes, int n_in,
                              void* d_out, int out_size, void* d_ws, size_t ws_size,
                              hipStream_t stream) {
    const float* x     = (const float*)d_in[0];
    const float* ln1_g = (const float*)d_in[1];
    const float* ln1_b = (const float*)d_in[2];
    const float* wq    = (const float*)d_in[3];
    const float* bq    = (const float*)d_in[4];
    const float* wk    = (const float*)d_in[5];
    const float* bk    = (const float*)d_in[6];
    const float* wv    = (const float*)d_in[7];
    const float* bv    = (const float*)d_in[8];
    const float* wo    = (const float*)d_in[9];
    const float* bo    = (const float*)d_in[10];
    const float* w1    = (const float*)d_in[11];
    const float* b1    = (const float*)d_in[12];
    const float* w2    = (const float*)d_in[13];
    const float* b2    = (const float*)d_in[14];
    const float* rc_w1 = (const float*)d_in[15];
    const float* rc_b1 = (const float*)d_in[16];
    const float* rc_w2 = (const float*)d_in[17];
    const float* rc_b2 = (const float*)d_in[18];
    const float* kg_w  = (const float*)d_in[19];
    const float* s2n_w = (const float*)d_in[20];
    const float* s2n_b = (const float*)d_in[21];
    const float* ln2_g = (const float*)d_in[22];
    const float* ln2_b = (const float*)d_in[23];
    float* out = (float*)d_out;

    const int BS  = B_ * S_;          // 512
    const int BSD = BS * D_;          // 262144

    // ---- Workspace (ws_size = 256 MB per harness fill evidence) ----
    unsigned short* wt = (unsigned short*)d_ws;
    const size_t E = 262144;          // 512*512
    unsigned short* qkv_h = wt;
    unsigned short* qkv_l = wt + 3 * E;
    unsigned short* wo_h  = wt + 6 * E;
    unsigned short* wo_l  = wt + 7 * E;
    unsigned short* w1_h  = wt + 8 * E;
    unsigned short* w1_l  = wt + 12 * E;
    unsigned short* w2_h  = wt + 16 * E;
    unsigned short* w2_l  = wt + 20 * E;
    unsigned short* rc_h  = wt + 24 * E;
    unsigned short* rc_l  = wt + 26 * E;
    unsigned short* kg_h  = wt + 28 * E;
    unsigned short* kg_l  = wt + 36 * E;
    unsigned short* s2_h  = wt + 44 * E;
    unsigned short* s2_l  = wt + 45 * E;
    size_t wt_words = 46 * E;

    int* rel    = (int*)(wt + wt_words);        // 65536 ints (pre-zeroed)
    int* ecount = rel + B_ * S_ * S_;           // 64 ints (pre-zeroed with rel)
    int* elist  = ecount + 64;                  // 65536 ints
    float* BIG  = (float*)(elist + B_ * S_ * S_);
    float* S0   = BIG + 2097152;
    float* S1   = S0 + BSD;
    float* S2   = S1 + BSD;
    float* S3   = S2 + BSD;
    float* S4   = S3 + BSD;

    float* xn       = S0;
    float* q        = S1;   // q,k,v in S1,S2,S3
    float* v_       = S3;
    float* attn     = BIG;
    float* ctx      = S4;
    float* attn_out = S0;
    float* hidden   = BIG;
    float* nu       = S2;
    float* a_part   = S0;   // a_part,b_part in S0,S1
    float* Mbuf     = BIG;
    float* y        = S0;

    // 0a. zero rel + ecount
    hipMemsetAsync(rel, 0, (size_t)(B_ * S_ * S_ + 64) * 4, stream);
    // 0b. transpose+split all weights
    TPack tp;
    int off = 0;
    auto setd = [&](int i, const float* s, unsigned short* h, unsigned short* l, int K, int N) {
        tp.d[i] = TDesc{s, h, l, K, N, off};
        off += (K / 32) * (N / 32);
    };
    setd(0, wq, qkv_h,         qkv_l,         D_, D_);
    setd(1, wk, qkv_h + E,     qkv_l + E,     D_, D_);
    setd(2, wv, qkv_h + 2 * E, qkv_l + 2 * E, D_, D_);
    setd(3, wo, wo_h, wo_l, D_, D_);
    setd(4, w1, w1_h, w1_l, D_, F_);
    setd(5, w2, w2_h, w2_l, F_, D_);
    setd(6, rc_w1,            rc_h,     rc_l,     D_, D_);
    setd(7, rc_w1 + D_ * D_,  rc_h + E, rc_l + E, D_, D_);
    setd(8, kg_w, kg_h, kg_l, R_ * D_, D_);
    setd(9, s2n_w, s2_h, s2_l, D_, D_);
    hipLaunchKernelGGL(transpose_split_kernel, dim3(off), dim3(256), 0, stream, tp);

    // 1. LN1
    hipLaunchKernelGGL(ln1_kernel, dim3(BS), dim3(256), 0, stream, x, ln1_g, ln1_b, xn);
    // 2. QKV (z-batched) -> S1,S2,S3
    hipLaunchKernelGGL(mgemm_zw_kernel, dim3(D_ / 64, BS / 64, 3), dim3(256), 0, stream,
                       xn, qkv_h, qkv_l, bq, bk, bv, q, BS, D_, D_);
    // 3. attention (wave-per-row) -> attn(BIG), ctx(S4)
    hipLaunchKernelGGL(attn_kernel, dim3(B_ * H_ * S_ / 4), dim3(256), 0, stream,
                       q, q + BSD, v_, attn, ctx);
    hipMemsetAsync(nu, 0, (size_t)BSD * 4, stream);   // k dead; FFN2 atomic target
    // 4. adjacency + edge compaction
    hipLaunchKernelGGL(adjc_kernel, dim3(B_ * S_ * S_ / 256), dim3(256), 0, stream,
                       attn, ecount, elist);
    // 5. wo: ctx -> attn_out
    hipLaunchKernelGGL(mgemm_kernel, dim3(D_ / 64, BS / 64), dim3(256), 0, stream,
                       ctx, wo_h, wo_l, bo, attn_out, D_, D_, 0);
    // 6. FFN1 (relu): attn_out -> hidden
    hipLaunchKernelGGL(mgemm_kernel, dim3(F_ / 64, BS / 64), dim3(256), 0, stream,
                       attn_out, w1_h, w1_l, b1, hidden, F_, D_, 1);
    // 7. FFN2 split-K=4 -> nu (zeroed)
    hipLaunchKernelGGL(mgemm_sk_kernel, dim3(D_ / 64, BS / 64, 4), dim3(256), 0, stream,
                       hidden, w2_h, w2_l, b2, nu, D_, F_);
    // 8. rc halves (z-batched) -> a_part,b_part
    hipLaunchKernelGGL(mgemm_zw_kernel, dim3(D_ / 64, BS / 64, 2), dim3(256), 0, stream,
                       nu, rc_h, rc_l, (const float*)nullptr, (const float*)nullptr,
                       (const float*)nullptr, a_part, BS, D_, D_);
    // 9. edges (persistent over compacted list)
    hipLaunchKernelGGL(edge_kernel, dim3(256), dim3(64), 0, stream,
                       a_part, a_part + BSD, rc_b1, rc_w2, rc_b2, elist, ecount, rel);
    // 10. RGCN aggregate (LDS) -> Mbuf
    hipLaunchKernelGGL(mbuild_kernel, dim3(BS), dim3(128), 0, stream, nu, rel, Mbuf);
    // 11. Mbuf @ kg_w split-K=8, atomicAdd directly into nu (reasoned = nu + agg)
    hipLaunchKernelGGL(mgemm_sk_kernel, dim3(D_ / 64, BS / 64, 8), dim3(256), 0, stream,
                       Mbuf, kg_h, kg_l, (const float*)nullptr, nu, D_, R_ * D_);
    // 13. s2n: nu -> y
    hipLaunchKernelGGL(mgemm_kernel, dim3(D_ / 64, BS / 64), dim3(256), 0, stream,
                       nu, s2_h, s2_l, s2n_b, y, D_, D_, 0);
    // 14. LN2 -> out
    hipLaunchKernelGGL(ln2_kernel, dim3(BS), dim3(256), 0, stream, x, y, ln2_g, ln2_b, out);
}